// Round 4
// baseline (28.436 us; speedup 1.0000x reference)
//
#include <hip/hip_runtime.h>

#define N_ATOMS 262144
#define N_MOL   8192
#define MAX_Z   100
#define D       1024
#define NDOT    (MAX_Z + 3)      // 103 rows: 100 embed + 3 w_pos
#define NBLK    256
#define NTHR    512
#define MPB     (N_MOL / NBLK)   // 32 molecules owned per block
#define NPRODB  26               // blocks 0..25: waves 2..5 produce rows

// Module globals (NOT d_ws: harness poisons d_ws to 0xAA before timing).
// Loader zero-inits; end-of-kernel reset keeps them 0 across graph replays.
__device__ int g_ready = 0;   // producer rows published (target NDOT)
__device__ int g_done  = 0;   // blocks finished (target NBLK)

__global__ __launch_bounds__(NTHR) void fused_energy_kernel(
    const int* __restrict__ z, const float* __restrict__ pos,
    const int* __restrict__ batch,
    const float* __restrict__ embed, const float* __restrict__ w_pos,
    const float* __restrict__ w, const float* __restrict__ b,
    float* __restrict__ out, float* __restrict__ ws)
{
    const int blk  = blockIdx.x, tid = threadIdx.x;
    const int lane = tid & 63,   wv  = tid >> 6;
    __shared__ float tab[NDOT];
    __shared__ float mol[MPB];
    __shared__ int   bounds[2];

    if (tid >= 64 * 6 && tid < 64 * 6 + MPB) mol[tid - 64 * 6] = 0.f;

    const int mol_base = blk * MPB;

    // ---- waves 0,1 (every block): 64-ary lower_bound of owned range ----
    // batch sorted, N_ATOMS = 64^3 exactly.
    if (wv < 2) {
        const int V = mol_base + wv * MPB;   // wv=0: start, wv=1: end
        int lower;
        int v1 = batch[lane * 4096];
        int c1 = __popcll(__ballot(v1 < V));
        if (c1 == 0) {
            lower = 0;
        } else {
            int base1 = (c1 - 1) * 4096;
            int idx2  = base1 + (lane + 1) * 64;
            int v2    = (idx2 < N_ATOMS) ? batch[idx2] : 0x7fffffff;
            int c2    = __popcll(__ballot(v2 < V));
            int base2 = base1 + c2 * 64;
            int idx3  = base2 + 1 + lane;
            int v3    = (idx3 < N_ATOMS) ? batch[idx3] : 0x7fffffff;
            int c3    = __popcll(__ballot(v3 < V));
            lower = base2 + 1 + c3;
        }
        if (lane == 0) bounds[wv] = lower;
    }

    // ---- waves 2..5 of blocks 0..25: produce one dot row each ----
    if (blk < NPRODB && wv >= 2 && wv < 6) {
        const int r = blk * 4 + (wv - 2);
        if (r < NDOT) {
            const float* row = (r < MAX_Z) ? embed + (size_t)r * D
                                           : w_pos + (size_t)(r - MAX_Z) * D;
            float s = 0.f;
            #pragma unroll
            for (int k = 0; k < 4; ++k) {
                float4 rv = *(const float4*)&row[4 * lane + 256 * k];
                float4 wc = *(const float4*)&w[4 * lane + 256 * k];
                s += rv.x * wc.x + rv.y * wc.y + rv.z * wc.z + rv.w * wc.w;
            }
            #pragma unroll
            for (int off = 32; off > 0; off >>= 1)
                s += __shfl_xor(s, off);
            if (lane == 0) {
                __hip_atomic_store(&ws[r], s, __ATOMIC_RELEASE,
                                   __HIP_MEMORY_SCOPE_AGENT);
                __hip_atomic_fetch_add(&g_ready, 1, __ATOMIC_RELEASE,
                                       __HIP_MEMORY_SCOPE_AGENT);
            }
        }
    }
    __syncthreads();

    // ---- single-thread acquire-poll for all 103 rows ----
    if (tid == 0) {
        while (__hip_atomic_load(&g_ready, __ATOMIC_ACQUIRE,
                                 __HIP_MEMORY_SCOPE_AGENT) < NDOT)
            __builtin_amdgcn_s_sleep(8);
    }
    __syncthreads();

    // ---- broadcast table to LDS (agent loads bypass stale local caches) ----
    if (tid < NDOT)
        tab[tid] = __hip_atomic_load(&ws[tid], __ATOMIC_RELAXED,
                                     __HIP_MEMORY_SCOPE_AGENT);
    __syncthreads();

    // ---- atom phase: owned range only ----
    const int lower = bounds[0], upper = bounds[1];
    const float pw0 = tab[MAX_Z + 0];
    const float pw1 = tab[MAX_Z + 1];
    const float pw2 = tab[MAX_Z + 2];

    for (int base = lower; base < upper; base += NTHR) {
        const int  i     = base + tid;
        const bool valid = i < upper;
        const int  ii    = valid ? i : (upper - 1);

        const int   id = valid ? batch[ii] : 0x7fffffff;
        const int   zi = z[ii];
        const float p0 = pos[3 * (size_t)ii + 0];
        const float p1 = pos[3 * (size_t)ii + 1];
        const float p2 = pos[3 * (size_t)ii + 2];
        float v = valid ? (tab[zi] + p0 * pw0 + p1 * pw1 + p2 * pw2) : 0.f;

        // segmented inclusive scan across the 64-lane wave (batch sorted)
        #pragma unroll
        for (int off = 1; off < 64; off <<= 1) {
            float vu = __shfl_up(v, off);
            int   iu = __shfl_up(id, off);
            if (lane >= off && iu == id) v += vu;
        }
        const int idn = __shfl_down(id, 1);
        if (valid && (lane == 63 || idn != id))
            atomicAdd(&mol[id - mol_base], v);
    }
    __syncthreads();

    // ---- exactly-once output write ----
    if (tid < MPB) out[mol_base + tid] = b[0] + mol[tid];

    // ---- reset protocol: keep counters 0 across graph replays ----
    if (tid == 0) {
        int old = __hip_atomic_fetch_add(&g_done, 1, __ATOMIC_ACQ_REL,
                                         __HIP_MEMORY_SCOPE_AGENT);
        if (old == NBLK - 1) {   // last block: everyone already passed the poll
            __hip_atomic_store(&g_ready, 0, __ATOMIC_RELAXED,
                               __HIP_MEMORY_SCOPE_AGENT);
            __hip_atomic_store(&g_done, 0, __ATOMIC_RELAXED,
                               __HIP_MEMORY_SCOPE_AGENT);
        }
    }
}

extern "C" void kernel_launch(void* const* d_in, const int* in_sizes, int n_in,
                              void* d_out, int out_size, void* d_ws, size_t ws_size,
                              hipStream_t stream) {
    const int*   atomic_numbers = (const int*)d_in[0];
    const float* pos            = (const float*)d_in[1];
    const int*   batch          = (const int*)d_in[2];
    const float* embed          = (const float*)d_in[3];
    const float* w_pos          = (const float*)d_in[4];
    const float* w              = (const float*)d_in[5];
    const float* b              = (const float*)d_in[6];
    float*       out            = (float*)d_out;
    float*       ws             = (float*)d_ws;

    fused_energy_kernel<<<NBLK, NTHR, 0, stream>>>(
        atomic_numbers, pos, batch, embed, w_pos, w, b, out, ws);
}

// Round 5
// 14.806 us; speedup vs baseline: 1.9206x; 1.9206x over previous
//
#include <hip/hip_runtime.h>

#define N_ATOMS 262144
#define N_MOL   8192
#define MAX_Z   100
#define D       1024
#define NDOT    (MAX_Z + 3)        // 100 embed rows + 3 w_pos rows
#define K2_BLK  512
#define K2_THR  256
#define MPB     (N_MOL / K2_BLK)   // 16 molecules owned per block

// ---------- kernel 1: 103 dot products, one wave per row, no barriers ------
__global__ __launch_bounds__(64) void table_kernel(
    const float* __restrict__ embed, const float* __restrict__ w_pos,
    const float* __restrict__ w, float* __restrict__ tab)
{
    const int r    = blockIdx.x;
    const int lane = threadIdx.x;
    const float* row = (r < MAX_Z) ? embed + (size_t)r * D
                                   : w_pos + (size_t)(r - MAX_Z) * D;
    float s = 0.f;
    #pragma unroll
    for (int k = 0; k < 4; ++k) {
        float4 rv = *(const float4*)&row[4 * lane + 256 * k];
        float4 wv = *(const float4*)&w[4 * lane + 256 * k];
        s += rv.x * wv.x + rv.y * wv.y + rv.z * wv.z + rv.w * wv.w;
    }
    #pragma unroll
    for (int off = 32; off > 0; off >>= 1) s += __shfl_xor(s, off);
    if (lane == 0) tab[r] = s;
}

// ---------- kernel 2: block-owned molecules, search + scan + exact write ---
__global__ __launch_bounds__(K2_THR) void atom_kernel(
    const int* __restrict__ z, const float* __restrict__ pos,
    const int* __restrict__ batch, const float* __restrict__ b,
    const float* __restrict__ ws, float* __restrict__ out)
{
    const int blk  = blockIdx.x, tid = threadIdx.x;
    const int lane = tid & 63,   wv  = tid >> 6;
    __shared__ float tab[NDOT];
    __shared__ float mol[MPB];
    __shared__ int   bounds[2];

    const int mol_base = blk * MPB;

    // waves 0,1: 64-ary lower_bound (batch sorted, N_ATOMS = 64^3 exactly)
    if (wv < 2) {
        const int V = mol_base + wv * MPB;   // wv=0: range start, wv=1: end
        int lower;
        int v1 = batch[lane * 4096];
        int c1 = __popcll(__ballot(v1 < V));
        if (c1 == 0) {
            lower = 0;
        } else {
            int base1 = (c1 - 1) * 4096;
            int idx2  = base1 + (lane + 1) * 64;
            int v2    = (idx2 < N_ATOMS) ? batch[idx2] : 0x7fffffff;
            int c2    = __popcll(__ballot(v2 < V));
            int base2 = base1 + c2 * 64;
            int idx3  = base2 + 1 + lane;
            int v3    = (idx3 < N_ATOMS) ? batch[idx3] : 0x7fffffff;
            int c3    = __popcll(__ballot(v3 < V));
            lower = base2 + 1 + c3;
        }
        if (lane == 0) bounds[wv] = lower;
    } else {
        // waves 2,3: stage the 103-entry table (stream-order visible) + zero mol
        const int k = tid - 128;
        if (k < NDOT) tab[k] = ws[k];
        if (k >= NDOT && k - NDOT < MPB) mol[k - NDOT] = 0.f;
    }
    __syncthreads();

    const int lower = bounds[0], upper = bounds[1];
    const float pw0 = tab[MAX_Z + 0];
    const float pw1 = tab[MAX_Z + 1];
    const float pw2 = tab[MAX_Z + 2];

    for (int base = lower; base < upper; base += K2_THR) {
        const int  i     = base + tid;
        const bool valid = i < upper;
        const int  ii    = valid ? i : (upper - 1);

        const int   id = valid ? batch[ii] : 0x7fffffff;
        const int   zi = z[ii];
        const float p0 = pos[3 * (size_t)ii + 0];
        const float p1 = pos[3 * (size_t)ii + 1];
        const float p2 = pos[3 * (size_t)ii + 2];
        float v = valid ? (tab[zi] + p0 * pw0 + p1 * pw1 + p2 * pw2) : 0.f;

        // segmented inclusive scan across the 64-lane wave (batch sorted)
        #pragma unroll
        for (int off = 1; off < 64; off <<= 1) {
            float vu = __shfl_up(v, off);
            int   iu = __shfl_up(id, off);
            if (lane >= off && iu == id) v += vu;
        }
        const int idn = __shfl_down(id, 1);
        if (valid && (lane == 63 || idn != id))
            atomicAdd(&mol[id - mol_base], v);   // LDS atomic, few per wave
    }
    __syncthreads();

    // exactly-once output write: no init pass, no global atomics
    if (tid < MPB) out[mol_base + tid] = b[0] + mol[tid];
}

extern "C" void kernel_launch(void* const* d_in, const int* in_sizes, int n_in,
                              void* d_out, int out_size, void* d_ws, size_t ws_size,
                              hipStream_t stream) {
    const int*   atomic_numbers = (const int*)d_in[0];
    const float* pos            = (const float*)d_in[1];
    const int*   batch          = (const int*)d_in[2];
    const float* embed          = (const float*)d_in[3];
    const float* w_pos          = (const float*)d_in[4];
    const float* w              = (const float*)d_in[5];
    const float* b              = (const float*)d_in[6];
    float*       out            = (float*)d_out;
    float*       tab            = (float*)d_ws;

    table_kernel<<<NDOT, 64, 0, stream>>>(embed, w_pos, w, tab);
    atom_kernel<<<K2_BLK, K2_THR, 0, stream>>>(atomic_numbers, pos, batch,
                                               b, tab, out);
}

// Round 6
// 12.026 us; speedup vs baseline: 2.3645x; 1.2311x over previous
//
#include <hip/hip_runtime.h>

#define N_ATOMS 262144
#define N_MOL   8192
#define MAX_Z   100
#define D       1024
#define NDOT    (MAX_Z + 3)      // 100 embed rows + 3 w_pos rows
#define NINIT   8                // out-init blocks in kernel 1
#define K2_THR  256
#define APT     4                // atoms per thread
#define K2_BLK  (N_ATOMS / (K2_THR * APT))   // 256 blocks

// ---------- kernel 1: one wave per dot row + out init, no barriers --------
__global__ __launch_bounds__(64) void table_kernel(
    const float* __restrict__ embed, const float* __restrict__ w_pos,
    const float* __restrict__ w, const float* __restrict__ b,
    float* __restrict__ tab, float* __restrict__ out)
{
    const int r    = blockIdx.x;
    const int lane = threadIdx.x;

    if (r < NDOT) {
        const float* row = (r < MAX_Z) ? embed + (size_t)r * D
                                       : w_pos + (size_t)(r - MAX_Z) * D;
        float s = 0.f;
        #pragma unroll
        for (int k = 0; k < 4; ++k) {
            float4 rv = *(const float4*)&row[4 * lane + 256 * k];
            float4 wv = *(const float4*)&w[4 * lane + 256 * k];
            s += rv.x * wv.x + rv.y * wv.y + rv.z * wv.z + rv.w * wv.w;
        }
        #pragma unroll
        for (int off = 32; off > 0; off >>= 1) s += __shfl_xor(s, off);
        if (lane == 0) tab[r] = s;
    } else {
        // out[m] = b  (atomics in kernel 2 accumulate on top; rewritten
        // every call so graph replays are deterministic)
        const float bv  = b[0];
        float4      bv4 = make_float4(bv, bv, bv, bv);
        float4*     o4  = (float4*)out + (size_t)(r - NDOT) * (N_MOL / 4 / NINIT);
        #pragma unroll
        for (int k = 0; k < N_MOL / 4 / NINIT / 64; ++k)
            o4[lane + 64 * k] = bv4;
    }
}

// ---------- kernel 2: 4 atoms/thread, two-level segmented reduction -------
__global__ __launch_bounds__(K2_THR) void atom_kernel(
    const int* __restrict__ z, const float* __restrict__ pos,
    const int* __restrict__ batch, const float* __restrict__ tabg,
    float* __restrict__ out)
{
    const int tid  = threadIdx.x;
    const int lane = tid & 63;
    const int i0   = (blockIdx.x * K2_THR + tid) * APT;

    // issue all atom loads before the LDS stage so they overlap it
    const int4   ids = *(const int4*)(batch + i0);
    const int4   zs  = *(const int4*)(z + i0);
    const float4 pa  = *(const float4*)(pos + (size_t)3 * i0);
    const float4 pb  = *(const float4*)(pos + (size_t)3 * i0 + 4);
    const float4 pc  = *(const float4*)(pos + (size_t)3 * i0 + 8);

    __shared__ float tab[NDOT];
    if (tid < NDOT) tab[tid] = tabg[tid];
    __syncthreads();

    const float pw0 = tab[MAX_Z + 0];
    const float pw1 = tab[MAX_Z + 1];
    const float pw2 = tab[MAX_Z + 2];

    const float v0 = tab[zs.x] + pa.x * pw0 + pa.y * pw1 + pa.z * pw2;
    const float v1 = tab[zs.y] + pa.w * pw0 + pb.x * pw1 + pb.y * pw2;
    const float v2 = tab[zs.z] + pb.z * pw0 + pb.w * pw1 + pc.x * pw2;
    const float v3 = tab[zs.w] + pc.y * pw0 + pc.z * pw1 + pc.w * pw2;

    // ---- level 1: sequential run-merge over this thread's 4 sorted atoms.
    // First closed run is the head (may continue from previous lane);
    // other closed runs are interior to this thread -> emit directly.
    const int h_id = ids.x;
    float h_sum = 0.f;
    bool  split = false;
    int   cur = ids.x;
    float run = v0;
    #define STEP(idk, vk)                                                    \
        if ((idk) == cur) { run += (vk); }                                   \
        else {                                                               \
            if (!split) { h_sum = run; split = true; }                       \
            else atomicAdd(&out[cur], run);                                  \
            cur = (idk); run = (vk);                                         \
        }
    STEP(ids.y, v1)
    STEP(ids.z, v2)
    STEP(ids.w, v3)
    #undef STEP
    const int   t_id  = cur;
    const float t_sum = run;

    // ---- level 2: wave inclusive segmented scan on tail runs.
    // t_id is non-decreasing across lanes (batch sorted), so key-equality
    // Hillis-Steele is a valid segmented scan.
    float s = t_sum;
    #pragma unroll
    for (int off = 1; off < 64; off <<= 1) {
        float su = __shfl_up(s, off);
        int   tu = __shfl_up(t_id, off);
        if (lane >= off && tu == t_id) s += su;
    }
    const float ps = __shfl_up(s, 1);
    const int   pt = __shfl_up(t_id, 1);
    const int   nh = __shfl_down(h_id, 1);

    // head emission: closes the segment arriving from previous lanes
    if (split) {
        float hv = h_sum + ((lane > 0 && pt == h_id) ? ps : 0.f);
        atomicAdd(&out[h_id], hv);
    }
    // tail emission: only if the next lane does not absorb my running sum
    if (lane == 63 || nh != t_id)
        atomicAdd(&out[t_id], s);
}

extern "C" void kernel_launch(void* const* d_in, const int* in_sizes, int n_in,
                              void* d_out, int out_size, void* d_ws, size_t ws_size,
                              hipStream_t stream) {
    const int*   atomic_numbers = (const int*)d_in[0];
    const float* pos            = (const float*)d_in[1];
    const int*   batch          = (const int*)d_in[2];
    const float* embed          = (const float*)d_in[3];
    const float* w_pos          = (const float*)d_in[4];
    const float* w              = (const float*)d_in[5];
    const float* b              = (const float*)d_in[6];
    float*       out            = (float*)d_out;
    float*       tab            = (float*)d_ws;

    table_kernel<<<NDOT + NINIT, 64, 0, stream>>>(embed, w_pos, w, b, tab, out);
    atom_kernel<<<K2_BLK, K2_THR, 0, stream>>>(atomic_numbers, pos, batch,
                                               tab, out);
}